// Round 2
// baseline (190.275 us; speedup 1.0000x reference)
//
#include <hip/hip_runtime.h>

// SpMM (COO): out[rows[e], :] += vals[e] * annotations[cols[e], :]
// N=40000 nodes, E=640000 edges, D=128 feats, fp32 in/out.
//
// Round 6: attack the scatter critical path + pull locality.
//   - pairs stores are CACHEABLE again (round-5 NT stores caused 8x write
//     amplification: 42.8 MB = E * 64B partial lines).
//   - scatter: 1 edge/thread (2500 WGs, was 625) for max waves/outstanding
//     atomics; cursor padded to 1 counter per 64B line (no line-granular
//     serialization at the atomic coherence point).
//   - convert fused into the scatter dispatch (independent work, hides
//     under the latency-bound scatter). Cursor zeroing via tiny memset DMA.
//   - pull: 4 column-range passes with pairs held in registers; each pass
//     gathers from a 2.56 MB annb slice that fits per-XCD L2 (4 MiB).
//     out stores + pairs loads stay NT so L2 is dedicated to annb.

constexpr int N_NODES = 40000;
constexpr int N_EDGES = 640000;
constexpr int D_FEAT  = 128;
constexpr int CAP     = 32;       // slots per row; deg>CAP spills to overflow
constexpr int OVF_CAP = 16384;
constexpr int CSTR    = 16;       // cursor stride (ints): 1 counter per 64B line
constexpr int NPASS   = 4;
constexpr int PASS_W  = N_NODES / NPASS;   // 10000 cols per pass

// ---- workspace layout (bytes) ----
constexpr size_t WS_CURSOR = 0;                         // int[N*CSTR] = 2,560,000
constexpr size_t WS_OVFCNT = 2560000;                   // int
constexpr size_t WS_OVF    = 2560256;                   // int4[OVF_CAP] = 262,144
constexpr size_t WS_ANNB   = 2822400;                   // bf16[N*D] as uint[N*64]
constexpr size_t WS_PAIRS  = 13062400;                  // int2[N*CAP] = 10,240,000
constexpr size_t WS_ZERO   = 2560256;                   // bytes to memset (cursor+ovfcnt)
constexpr size_t WS_NEEDED = 23302400;

constexpr int SCAT_BLOCKS = N_EDGES / 256;              // 2500 (1 edge/thread)
constexpr int CONV_BLOCKS = (N_NODES * D_FEAT / 8) / 256; // 2500 (8 floats/thread)

typedef int      v2i __attribute__((ext_vector_type(2)));
typedef float    v2f __attribute__((ext_vector_type(2)));
typedef float    v4f __attribute__((ext_vector_type(4)));
typedef unsigned v4u __attribute__((ext_vector_type(4)));

__device__ __forceinline__ unsigned f2b_rne(float f) {
    unsigned b = __float_as_uint(f);
    return (b + 0x7fffu + ((b >> 16) & 1u)) >> 16;
}

// Fused scatter + convert. Scatter blocks first (they are the critical path);
// convert blocks fill in behind them.
__global__ __launch_bounds__(256) void build_kernel(
    const int*   __restrict__ rows,
    const int*   __restrict__ cols,
    const float* __restrict__ vals,
    const float* __restrict__ ann,
    unsigned*    __restrict__ annb,      // uint[N*64]
    int* __restrict__ cursor, v2i* __restrict__ pairs,
    int* __restrict__ ovfcnt, int4* __restrict__ ovf)
{
    if (blockIdx.x < SCAT_BLOCKS) {
        int e = blockIdx.x * 256 + threadIdx.x;
        int   r = __builtin_nontemporal_load(rows + e);
        int   c = __builtin_nontemporal_load(cols + e);
        float v = __builtin_nontemporal_load(vals + e);
        int slot = atomicAdd(&cursor[r * CSTR], 1);
        if (slot < CAP) {
            v2i p;
            p.x = c;
            p.y = __float_as_int(v);
            pairs[r * CAP + slot] = p;             // cacheable: L2 write-combines
        } else {
            int o = atomicAdd(ovfcnt, 1);
            if (o < OVF_CAP) ovf[o] = make_int4(r, c, __float_as_int(v), 0);
        }
    } else {
        // fp32 -> bf16 (RNE), 8 floats / thread, 16B store.
        int t = (blockIdx.x - SCAT_BLOCKS) * 256 + threadIdx.x;
        v4f f0 = __builtin_nontemporal_load(reinterpret_cast<const v4f*>(ann) + 2 * t);
        v4f f1 = __builtin_nontemporal_load(reinterpret_cast<const v4f*>(ann) + 2 * t + 1);
        v4u o;
        o.x = f2b_rne(f0.x) | (f2b_rne(f0.y) << 16);
        o.y = f2b_rne(f0.z) | (f2b_rne(f0.w) << 16);
        o.z = f2b_rne(f1.x) | (f2b_rne(f1.y) << 16);
        o.w = f2b_rne(f1.z) | (f2b_rne(f1.w) << 16);
        reinterpret_cast<v4u*>(annb)[t] = o;       // re-read by pull: cacheable
    }
}

// One wave (64 lanes) per row; lane owns feats [2l, 2l+1] (one uint = 2 bf16).
// pairs lane-loaded once (lanes 0..31), shfl-broadcast, held in registers
// across NPASS column-range passes so each pass's gathers hit a 2.56 MB
// annb slice (fits per-XCD L2). Lanes >= cnt default to {col 0, val 0}:
// they fall in pass 0's range and add v*x = 0 (tail-safe).
__global__ __launch_bounds__(256) void pull_kernel(
    const unsigned* __restrict__ annb,   // uint[N*64]
    const int*      __restrict__ cursor,
    const v2i*      __restrict__ pairs,
    const int*      __restrict__ ovfcnt,
    const int4*     __restrict__ ovf,
    float*          __restrict__ out)
{
    int r    = (blockIdx.x * blockDim.x + threadIdx.x) >> 6;
    int lane = threadIdx.x & 63;
    // grid is exactly N_NODES*64 threads: no early-out, all lanes active.

    int cntr = cursor[r * CSTR];
    int cnt  = cntr > CAP ? CAP : cntr;

    int2 pr = make_int2(0, 0);                     // col 0, val 0.0f
    if (lane < cnt) {
        v2i p = __builtin_nontemporal_load(pairs + (r * CAP + lane));
        pr.x = p.x;
        pr.y = p.y;
    }

    float2 acc = make_float2(0.f, 0.f);
    int nb = (cnt + 7) & ~7;
    for (int pass = 0; pass < NPASS; pass++) {
        int lo = pass * PASS_W;
        int hi = lo + PASS_W;
        for (int j = 0; j < nb; j += 8) {
            #pragma unroll
            for (int k = 0; k < 8; k++) {
                int c = __shfl(pr.x, j + k, 64);   // wave-uniform
                if (c >= lo && c < hi) {           // uniform branch: safe w/ shfl
                    float    v = __int_as_float(__shfl(pr.y, j + k, 64));
                    unsigned p = annb[c * (D_FEAT / 2) + lane];
                    acc.x += v * __uint_as_float(p << 16);
                    acc.y += v * __uint_as_float(p & 0xffff0000u);
                }
            }
        }
    }

    if (cntr > CAP) {                              // ~6 rows expected; tiny scan
        int n = *ovfcnt;
        n = n > OVF_CAP ? OVF_CAP : n;
        for (int i = 0; i < n; i++) {
            int4 e = ovf[i];                       // wave-uniform broadcast load
            if (e.x == r) {
                unsigned p = annb[e.y * (D_FEAT / 2) + lane];
                float    v = __int_as_float(e.z);
                acc.x += v * __uint_as_float(p << 16);
                acc.y += v * __uint_as_float(p & 0xffff0000u);
            }
        }
    }

    v2f o;
    o.x = acc.x;
    o.y = acc.y;
    __builtin_nontemporal_store(
        o, reinterpret_cast<v2f*>(out) + ((size_t)r * (D_FEAT / 2) + lane));
}

// ---- round-1 fallback (ws too small) ----
__global__ __launch_bounds__(256) void spmm_scatter_kernel(
    const int*   __restrict__ rows,
    const int*   __restrict__ cols,
    const float* __restrict__ vals,
    const float* __restrict__ ann,
    float*       __restrict__ out)
{
    int t = blockIdx.x * blockDim.x + threadIdx.x;
    int e = t >> 5;
    if (e >= N_EDGES) return;
    int lane = t & 31;
    int   r = rows[e];
    int   c = cols[e];
    float v = vals[e];
    float4 a = reinterpret_cast<const float4*>(ann)[(size_t)c * (D_FEAT / 4) + lane];
    float* o = out + (size_t)r * D_FEAT + lane * 4;
    unsafeAtomicAdd(o + 0, v * a.x);
    unsafeAtomicAdd(o + 1, v * a.y);
    unsafeAtomicAdd(o + 2, v * a.z);
    unsafeAtomicAdd(o + 3, v * a.w);
}

extern "C" void kernel_launch(void* const* d_in, const int* in_sizes, int n_in,
                              void* d_out, int out_size, void* d_ws, size_t ws_size,
                              hipStream_t stream) {
    const int*   rows = (const int*)  d_in[0];
    const int*   cols = (const int*)  d_in[1];
    const float* vals = (const float*)d_in[2];
    const float* ann  = (const float*)d_in[3];
    float*       out  = (float*)      d_out;

    if (ws_size < WS_NEEDED) {
        hipMemsetAsync(out, 0, (size_t)out_size * sizeof(float), stream);
        const long long total_threads = (long long)N_EDGES * 32;
        spmm_scatter_kernel<<<dim3((unsigned)((total_threads + 255) / 256)),
                              dim3(256), 0, stream>>>(rows, cols, vals, ann, out);
        return;
    }

    char*     ws     = (char*)d_ws;
    int*      cursor = (int*)     (ws + WS_CURSOR);
    int*      ovfcnt = (int*)     (ws + WS_OVFCNT);
    int4*     ovf    = (int4*)    (ws + WS_OVF);
    unsigned* annb   = (unsigned*)(ws + WS_ANNB);
    v2i*      pairs  = (v2i*)     (ws + WS_PAIRS);

    hipMemsetAsync(cursor, 0, WS_ZERO, stream);    // cursor + ovfcnt, DMA fill

    build_kernel<<<dim3(SCAT_BLOCKS + CONV_BLOCKS), dim3(256), 0, stream>>>(
        rows, cols, vals, ann, annb, cursor, pairs, ovfcnt, ovf);

    const long long pull_threads = (long long)N_NODES * 64;
    pull_kernel<<<dim3((unsigned)((pull_threads + 255) / 256)), dim3(256), 0, stream>>>(
        annb, cursor, pairs, ovfcnt, ovf, out);
}

// Round 3
// 143.130 us; speedup vs baseline: 1.3294x; 1.3294x over previous
//
#include <hip/hip_runtime.h>

// SpMM (COO): out[rows[e], :] += vals[e] * annotations[cols[e], :]
// N=40000 nodes, E=640000 edges, D=128 feats, fp32 in/out.
//
// Round 7: diagnostic round — separate kernels, keep only defensible fixes.
//   - pull reverted to single-pass (round-2's 4-pass cost 4x VALU for no
//     locality gain: FETCH stayed 57MB, VALUBusy 26%, dur 74us).
//   - scatter: 1 edge/thread (2500 WGs) + cursor padded to 1 counter per
//     64B line (round-1's 51us @ 0.3% VALU / 21% occ = same-line atomic
//     RMW serialization, ~250 serial ops/line unpadded -> 16 padded).
//   - pairs stores cacheable (NT partial-line stores were 8x write amp).
//   - convert separate again so every stage has a counter row.

constexpr int N_NODES = 40000;
constexpr int N_EDGES = 640000;
constexpr int D_FEAT  = 128;
constexpr int CAP     = 32;       // slots per row; deg>CAP spills to overflow
constexpr int OVF_CAP = 16384;
constexpr int CSTR    = 16;       // cursor stride (ints): 1 counter per 64B line

// ---- workspace layout (bytes) ----
constexpr size_t WS_CURSOR = 0;                         // int[N*CSTR] = 2,560,000
constexpr size_t WS_OVFCNT = 2560000;                   // int
constexpr size_t WS_OVF    = 2560256;                   // int4[OVF_CAP] = 262,144
constexpr size_t WS_ANNB   = 2822400;                   // bf16[N*D] as uint[N*64]
constexpr size_t WS_PAIRS  = 13062400;                  // int2[N*CAP] = 10,240,000
constexpr size_t WS_ZERO   = 2560256;                   // bytes to memset (cursor+ovfcnt)
constexpr size_t WS_NEEDED = 23302400;

typedef int      v2i __attribute__((ext_vector_type(2)));
typedef float    v2f __attribute__((ext_vector_type(2)));
typedef float    v4f __attribute__((ext_vector_type(4)));
typedef unsigned v4u __attribute__((ext_vector_type(4)));

__device__ __forceinline__ unsigned f2b_rne(float f) {
    unsigned b = __float_as_uint(f);
    return (b + 0x7fffu + ((b >> 16) & 1u)) >> 16;
}

// fp32 -> bf16 (RNE), 8 floats / thread, 16B store.
__global__ __launch_bounds__(256) void convert_kernel(
    const float* __restrict__ ann, unsigned* __restrict__ annb)
{
    int t = blockIdx.x * blockDim.x + threadIdx.x;
    v4f f0 = __builtin_nontemporal_load(reinterpret_cast<const v4f*>(ann) + 2 * t);
    v4f f1 = __builtin_nontemporal_load(reinterpret_cast<const v4f*>(ann) + 2 * t + 1);
    v4u o;
    o.x = f2b_rne(f0.x) | (f2b_rne(f0.y) << 16);
    o.y = f2b_rne(f0.z) | (f2b_rne(f0.w) << 16);
    o.z = f2b_rne(f1.x) | (f2b_rne(f1.y) << 16);
    o.w = f2b_rne(f1.z) | (f2b_rne(f1.w) << 16);
    reinterpret_cast<v4u*>(annb)[t] = o;       // re-read by pull: cacheable
}

// 1 edge/thread: max waves in flight for the atomic latency chain.
__global__ __launch_bounds__(256) void scatter_kernel(
    const int*   __restrict__ rows,
    const int*   __restrict__ cols,
    const float* __restrict__ vals,
    int* __restrict__ cursor, v2i* __restrict__ pairs,
    int* __restrict__ ovfcnt, int4* __restrict__ ovf)
{
    int e = blockIdx.x * blockDim.x + threadIdx.x;
    int   r = rows[e];
    int   c = cols[e];
    float v = vals[e];
    int slot = atomicAdd(&cursor[r * CSTR], 1);
    if (slot < CAP) {
        v2i p;
        p.x = c;
        p.y = __float_as_int(v);
        pairs[r * CAP + slot] = p;             // cacheable: L2 write-combines
    } else {
        int o = atomicAdd(ovfcnt, 1);
        if (o < OVF_CAP) ovf[o] = make_int4(r, c, __float_as_int(v), 0);
    }
}

// One wave (64 lanes) per row; lane owns feats [2l, 2l+1] (one uint = 2 bf16).
// pairs lane-loaded once (lanes 0..31), shfl-broadcast; zero-pair default for
// lanes >= cnt makes the 8x-unrolled batches tail-safe without zeroed memory.
// Rows with raw count > CAP additionally scan the overflow list in-register.
__global__ __launch_bounds__(256) void pull_kernel(
    const unsigned* __restrict__ annb,   // uint[N*64]
    const int*      __restrict__ cursor,
    const v2i*      __restrict__ pairs,
    const int*      __restrict__ ovfcnt,
    const int4*     __restrict__ ovf,
    float*          __restrict__ out)
{
    int r    = (blockIdx.x * blockDim.x + threadIdx.x) >> 6;
    int lane = threadIdx.x & 63;
    // grid is exactly N_NODES*64 threads: no early-out, all lanes active.

    int cntr = cursor[r * CSTR];
    int cnt  = cntr > CAP ? CAP : cntr;

    int2 pr = make_int2(0, 0);                     // col 0, val 0.0f
    if (lane < cnt) {
        v2i p = __builtin_nontemporal_load(pairs + (r * CAP + lane));
        pr.x = p.x;
        pr.y = p.y;
    }

    float2 acc = make_float2(0.f, 0.f);
    int nb = (cnt + 7) & ~7;
    for (int j = 0; j < nb; j += 8) {
        #pragma unroll
        for (int k = 0; k < 8; k++) {
            int      c = __shfl(pr.x, j + k, 64);
            float    v = __int_as_float(__shfl(pr.y, j + k, 64));
            unsigned p = annb[c * (D_FEAT / 2) + lane];
            acc.x += v * __uint_as_float(p << 16);
            acc.y += v * __uint_as_float(p & 0xffff0000u);
        }
    }

    if (cntr > CAP) {                              // ~6 rows expected; tiny scan
        int n = *ovfcnt;
        n = n > OVF_CAP ? OVF_CAP : n;
        for (int i = 0; i < n; i++) {
            int4 e = ovf[i];                       // wave-uniform broadcast load
            if (e.x == r) {
                unsigned p = annb[e.y * (D_FEAT / 2) + lane];
                float    v = __int_as_float(e.z);
                acc.x += v * __uint_as_float(p << 16);
                acc.y += v * __uint_as_float(p & 0xffff0000u);
            }
        }
    }

    v2f o;
    o.x = acc.x;
    o.y = acc.y;
    __builtin_nontemporal_store(
        o, reinterpret_cast<v2f*>(out) + ((size_t)r * (D_FEAT / 2) + lane));
}

// ---- fallback (ws too small) ----
__global__ __launch_bounds__(256) void spmm_scatter_kernel(
    const int*   __restrict__ rows,
    const int*   __restrict__ cols,
    const float* __restrict__ vals,
    const float* __restrict__ ann,
    float*       __restrict__ out)
{
    int t = blockIdx.x * blockDim.x + threadIdx.x;
    int e = t >> 5;
    if (e >= N_EDGES) return;
    int lane = t & 31;
    int   r = rows[e];
    int   c = cols[e];
    float v = vals[e];
    float4 a = reinterpret_cast<const float4*>(ann)[(size_t)c * (D_FEAT / 4) + lane];
    float* o = out + (size_t)r * D_FEAT + lane * 4;
    unsafeAtomicAdd(o + 0, v * a.x);
    unsafeAtomicAdd(o + 1, v * a.y);
    unsafeAtomicAdd(o + 2, v * a.z);
    unsafeAtomicAdd(o + 3, v * a.w);
}

extern "C" void kernel_launch(void* const* d_in, const int* in_sizes, int n_in,
                              void* d_out, int out_size, void* d_ws, size_t ws_size,
                              hipStream_t stream) {
    const int*   rows = (const int*)  d_in[0];
    const int*   cols = (const int*)  d_in[1];
    const float* vals = (const float*)d_in[2];
    const float* ann  = (const float*)d_in[3];
    float*       out  = (float*)      d_out;

    if (ws_size < WS_NEEDED) {
        hipMemsetAsync(out, 0, (size_t)out_size * sizeof(float), stream);
        const long long total_threads = (long long)N_EDGES * 32;
        spmm_scatter_kernel<<<dim3((unsigned)((total_threads + 255) / 256)),
                              dim3(256), 0, stream>>>(rows, cols, vals, ann, out);
        return;
    }

    char*     ws     = (char*)d_ws;
    int*      cursor = (int*)     (ws + WS_CURSOR);
    int*      ovfcnt = (int*)     (ws + WS_OVFCNT);
    int4*     ovf    = (int4*)    (ws + WS_OVF);
    unsigned* annb   = (unsigned*)(ws + WS_ANNB);
    v2i*      pairs  = (v2i*)     (ws + WS_PAIRS);

    hipMemsetAsync(cursor, 0, WS_ZERO, stream);    // cursor + ovfcnt, DMA fill

    convert_kernel<<<dim3((N_NODES * D_FEAT / 8 + 255) / 256), dim3(256), 0, stream>>>(
        ann, annb);

    scatter_kernel<<<dim3(N_EDGES / 256), dim3(256), 0, stream>>>(
        rows, cols, vals, cursor, pairs, ovfcnt, ovf);

    const long long pull_threads = (long long)N_NODES * 64;
    pull_kernel<<<dim3((unsigned)((pull_threads + 255) / 256)), dim3(256), 0, stream>>>(
        annb, cursor, pairs, ovfcnt, ovf, out);
}